// Round 1
// baseline (2141.194 us; speedup 1.0000x reference)
//
#include <hip/hip_runtime.h>
#include <hip/hip_bf16.h>
#include <stdint.h>

// ---------------------------------------------------------------------------
// QuantizedLinear: out = inp @ (q_w * scale_w[:,None]).T + bias
//   inp     [M,K]  fp32   (M = B*S = 8192, K = 4096)
//   quant_w [N,K]  int32  (int8-range values, exact in bf16)
//   scale_w [N]    fp32
//   bias    [N]    fp32
//   out     [M,N]  fp32
//
// Strategy: GEMM on UNSCALED weights in bf16 (int8 values exact in bf16),
// apply scale+bias per-column in fp32 epilogue. m97-ladder structure:
// 128x128 tile, BK=32, 16x16x32 bf16 MFMA, global_load_lds width-16.
// ---------------------------------------------------------------------------

typedef unsigned short u16;
using frag_t = __attribute__((ext_vector_type(8))) short;   // 8 bf16 (4 VGPRs)
using f32x4  = __attribute__((ext_vector_type(4))) float;   // MFMA C/D
using u16x8  = __attribute__((ext_vector_type(8))) u16;

#define BM 128
#define BN 128
#define BK 32

__device__ __forceinline__ void gld_lds16(const void* g, void* l) {
    __builtin_amdgcn_global_load_lds(
        (const __attribute__((address_space(1))) void*)g,
        (__attribute__((address_space(3))) void*)l,
        16, 0, 0);
}

// fp32 -> bf16 RTNE (inputs are normal floats; no NaN handling needed)
__device__ __forceinline__ u16 f2bf(float f) {
    uint32_t u = __builtin_bit_cast(uint32_t, f);
    u += 0x7fffu + ((u >> 16) & 1u);
    return (u16)(u >> 16);
}

// ---- prepass 1: fp32 -> bf16, 8 elements/thread ---------------------------
__global__ void cvt_f32_to_bf16(const float* __restrict__ in,
                                u16* __restrict__ out, long n8) {
    long i = (long)blockIdx.x * blockDim.x + threadIdx.x;
    if (i >= n8) return;
    long base = i * 8;
    const float4* p = (const float4*)(in + base);
    float4 f0 = p[0], f1 = p[1];
    u16x8 o;
    o[0] = f2bf(f0.x); o[1] = f2bf(f0.y); o[2] = f2bf(f0.z); o[3] = f2bf(f0.w);
    o[4] = f2bf(f1.x); o[5] = f2bf(f1.y); o[6] = f2bf(f1.z); o[7] = f2bf(f1.w);
    *(u16x8*)(out + base) = o;
}

// ---- prepass 2: int32 -> bf16 (exact for |v| <= 255), 8 elements/thread ---
__global__ void cvt_i32_to_bf16(const int* __restrict__ in,
                                u16* __restrict__ out, long n8) {
    long i = (long)blockIdx.x * blockDim.x + threadIdx.x;
    if (i >= n8) return;
    long base = i * 8;
    const int4* p = (const int4*)(in + base);
    int4 a = p[0], b = p[1];
    u16x8 o;
    o[0] = f2bf((float)a.x); o[1] = f2bf((float)a.y);
    o[2] = f2bf((float)a.z); o[3] = f2bf((float)a.w);
    o[4] = f2bf((float)b.x); o[5] = f2bf((float)b.y);
    o[6] = f2bf((float)b.z); o[7] = f2bf((float)b.w);
    *(u16x8*)(out + base) = o;
}

// ---- main GEMM: A[M,K] bf16 row-major, B[N,K] bf16 row-major (B^T input) --
// 256 threads = 4 waves in 2x2; each wave computes 64x64 (4x4 MFMA tiles).
__global__ __launch_bounds__(256)
void gemm_bf16_bt(const u16* __restrict__ A, const u16* __restrict__ B,
                  const float* __restrict__ scale, const float* __restrict__ bias,
                  float* __restrict__ C, int M, int N, int K) {
    __shared__ u16 As[BM * BK];   // 8192 B, row-major [128][32], no padding
    __shared__ u16 Bs[BN * BK];   // (global_load_lds needs contiguous lane order)

    const int tid  = threadIdx.x;
    const int wave = tid >> 6;
    const int lane = tid & 63;
    const int wm   = wave >> 1;   // 0..1 : wave row
    const int wn   = wave & 1;    // 0..1 : wave col

    const int row0 = blockIdx.y * BM;
    const int col0 = blockIdx.x * BN;

    // staging: thread t fills LDS bytes [t*16, t*16+16) (round 0) and
    // [4096 + t*16, ...) (round 1). Byte t*16 -> tile row t/4, k-elem (t%4)*8.
    const int sr = tid >> 2;            // staging row (0..63)
    const int sc = (tid & 3) * 8;       // staging k offset (elements)
    const u16* a_src0 = A + (long)(row0 + sr) * K + sc;
    const u16* a_src1 = A + (long)(row0 + 64 + sr) * K + sc;
    const u16* b_src0 = B + (long)(col0 + sr) * K + sc;
    const u16* b_src1 = B + (long)(col0 + 64 + sr) * K + sc;
    // wave-uniform LDS dest bases (lane*16 added by HW)
    u16* a_dst0 = As + wave * 512;          // wave covers 1024 B
    u16* a_dst1 = As + 2048 + wave * 512;
    u16* b_dst0 = Bs + wave * 512;
    u16* b_dst1 = Bs + 2048 + wave * 512;

    // fragment read addresses: A[m = lane&15][k = (lane>>4)*8 + j]
    const int frow = lane & 15;
    const int kof  = (lane >> 4) * 8;
    const u16* a_rd = As + (wm * 64 + frow) * BK + kof;
    const u16* b_rd = Bs + (wn * 64 + frow) * BK + kof;

    f32x4 acc[4][4] = {};

    for (int k0 = 0; k0 < K; k0 += BK) {
        gld_lds16(a_src0, a_dst0);
        gld_lds16(a_src1, a_dst1);
        gld_lds16(b_src0, b_dst0);
        gld_lds16(b_src1, b_dst1);
        a_src0 += BK; a_src1 += BK; b_src0 += BK; b_src1 += BK;
        __syncthreads();   // compiler emits vmcnt(0) drain before barrier

        frag_t af[4], bfr[4];
#pragma unroll
        for (int i = 0; i < 4; ++i) af[i]  = *(const frag_t*)(a_rd + i * 16 * BK);
#pragma unroll
        for (int j = 0; j < 4; ++j) bfr[j] = *(const frag_t*)(b_rd + j * 16 * BK);
#pragma unroll
        for (int i = 0; i < 4; ++i)
#pragma unroll
            for (int j = 0; j < 4; ++j)
                acc[i][j] = __builtin_amdgcn_mfma_f32_16x16x32_bf16(
                    af[i], bfr[j], acc[i][j], 0, 0, 0);
        __syncthreads();   // LDS reuse guard before next staging
    }

    // epilogue: C/D layout col = lane&15, row = (lane>>4)*4 + reg  [m89/m91]
    const int crow = wm * 64 + (lane >> 4) * 4;
    const int ccol = wn * 64 + (lane & 15);
    float sc4[4], bi4[4];
#pragma unroll
    for (int j = 0; j < 4; ++j) {
        sc4[j] = scale[col0 + ccol + j * 16];
        bi4[j] = bias[col0 + ccol + j * 16];
    }
#pragma unroll
    for (int i = 0; i < 4; ++i) {
#pragma unroll
        for (int r = 0; r < 4; ++r) {
            long grow = (long)(row0 + crow + i * 16 + r);
            float* cp = C + grow * N + col0 + ccol;
#pragma unroll
            for (int j = 0; j < 4; ++j)
                cp[j * 16] = acc[i][j][r] * sc4[j] + bi4[j];
        }
    }
}

extern "C" void kernel_launch(void* const* d_in, const int* in_sizes, int n_in,
                              void* d_out, int out_size, void* d_ws, size_t ws_size,
                              hipStream_t stream) {
    const float* inp   = (const float*)d_in[0];
    const int*   qw    = (const int*)d_in[1];
    const float* scale = (const float*)d_in[2];
    const float* bias  = (const float*)d_in[3];

    const long n_inp = (long)in_sizes[0];      // M*K
    const long n_w   = (long)in_sizes[1];      // N*K
    const int  N     = in_sizes[2];
    const int  K     = (int)(n_w / N);
    const int  M     = (int)(n_inp / K);

    u16* a_bf = (u16*)d_ws;              // M*K bf16  (64 MB)
    u16* b_bf = (u16*)d_ws + n_inp;      // N*K bf16  (128 MB)

    {
        long n8 = n_inp / 8;
        cvt_f32_to_bf16<<<(int)((n8 + 255) / 256), 256, 0, stream>>>(inp, a_bf, n8);
    }
    {
        long n8 = n_w / 8;
        cvt_i32_to_bf16<<<(int)((n8 + 255) / 256), 256, 0, stream>>>(qw, b_bf, n8);
    }

    dim3 grid(N / BN, M / BM);   // 128 x 64 = 8192 blocks
    gemm_bf16_bt<<<grid, 256, 0, stream>>>(a_bf, b_bf, scale, bias,
                                           (float*)d_out, M, N, K);
}